// Round 13
// baseline (768.179 us; speedup 1.0000x reference)
//
#include <hip/hip_runtime.h>

typedef __bf16 bf16_t;
typedef __bf16 bf16x4 __attribute__((ext_vector_type(4)));
typedef __bf16 bf16x8 __attribute__((ext_vector_type(8)));
typedef float f32x4 __attribute__((ext_vector_type(4)));

#define AS1 __attribute__((address_space(1)))
#define AS3 __attribute__((address_space(3)))
#define BAR() asm volatile("s_barrier" ::: "memory")
// pin VMEM/DS-write issue order; ALU/VALU/SALU/MFMA/DS_READ may cross
#define FENCE() __builtin_amdgcn_sched_barrier(0x10F)

__device__ __forceinline__ void gload_lds16(const void* g, void* l) {
  __builtin_amdgcn_global_load_lds((AS1 void*)g, (AS3 void*)l, 16, 0, 0);
}

// Stage a [128 rows x 32 cols] bf16 tile from row-major global (ld elems/row) into
// linear LDS [128][32]. 256 threads, 2 rounds of global_load_lds width-16.
__device__ __forceinline__ void stage_tile(const bf16_t* g, int ld, bf16_t* lds, int tid) {
  int w = tid >> 6, lane = tid & 63;
#pragma unroll
  for (int r = 0; r < 2; ++r) {
    int rowbase = r * 64 + w * 16;
    const bf16_t* gp = g + (long)(rowbase + (lane >> 2)) * ld + (lane & 3) * 8;
    bf16_t* lp = lds + rowbase * 32;  // wave-uniform; HW adds lane*16B
    gload_lds16(gp, lp);
  }
}

// C[128,128] tile of A[M,K] (rm) x Bt[N,K] (rm), 4 waves 2x2, 16x16x32 MFMA.
__device__ __forceinline__ void gemm_core(const bf16_t* A, const bf16_t* Bt, int lda, int ldb,
                                          int K, int rowBase, int colBase,
                                          bf16_t* As, bf16_t* Bs, f32x4 acc[4][4]) {
  int tid = threadIdx.x;
  int lane = tid & 63, w = tid >> 6;
  int wr = w >> 1, wc = w & 1;
  int lr = lane & 15, kg = lane >> 4;
  const bf16_t* Ab = A + (long)rowBase * lda;
  const bf16_t* Bb = Bt + (long)colBase * ldb;
  for (int kt = 0; kt < K; kt += 32) {
    __syncthreads();
    stage_tile(Ab + kt, lda, As, tid);
    stage_tile(Bb + kt, ldb, Bs, tid);
    __syncthreads();
    bf16x8 a[4], b[4];
#pragma unroll
    for (int m = 0; m < 4; ++m)
      a[m] = *(const bf16x8*)&As[(wr * 64 + m * 16 + lr) * 32 + kg * 8];
#pragma unroll
    for (int n = 0; n < 4; ++n)
      b[n] = *(const bf16x8*)&Bs[(wc * 64 + n * 16 + lr) * 32 + kg * 8];
#pragma unroll
    for (int m = 0; m < 4; ++m)
#pragma unroll
      for (int n = 0; n < 4; ++n)
        acc[m][n] = __builtin_amdgcn_mfma_f32_16x16x32_bf16(a[m], b[n], acc[m][n], 0, 0, 0);
  }
}

__device__ __forceinline__ void zero_acc(f32x4 acc[4][4]) {
#pragma unroll
  for (int m = 0; m < 4; ++m)
#pragma unroll
    for (int n = 0; n < 4; ++n)
#pragma unroll
      for (int i = 0; i < 4; ++i) acc[m][n][i] = 0.f;
}

// ===== 256x256 BK=64 free-running pipe (160KB LDS, 1 block/CU) — used by cache256 =====
__device__ __forceinline__ void pipe256(const bf16_t* __restrict__ Ag,
                                        const bf16_t* __restrict__ Bg,
                                        int K, int ntk, bf16_t* lds, f32x4 acc[8][4]) {
  int tid = threadIdx.x;
  int lane = tid & 63, w = tid >> 6;
  int wr = w >> 2, wc = w & 3;
  int lr = lane & 15, kg = lane >> 4;
  int colE = ((lane & 7) ^ (lane >> 3)) * 8;  // pre-swizzled global col (rule #21)
  int r0 = w * 16 + (lane >> 3);

  auto stageA = [&](int t, int h) {
    const bf16_t* g = Ag + (long)(h * 128 + r0) * K + t * 64 + colE;
    bf16_t* l = lds + (t & 1) * 16384 + h * 8192 + w * 1024;
    gload_lds16(g, l);
    gload_lds16(g + (long)8 * K, l + 512);
  };
  auto stageB = [&](int t, int h) {
    const bf16_t* g = Bg + (long)(h * 128 + r0) * K + t * 64 + colE;
    bf16_t* l = lds + 32768 + (t % 3) * 16384 + h * 8192 + w * 1024;
    gload_lds16(g, l);
    gload_lds16(g + (long)8 * K, l + 512);
  };

  stageB(0, 0); stageB(0, 1);
  FENCE();
  stageA(0, 0); stageA(0, 1);
  FENCE();
  if (ntk > 1) { stageB(1, 0); stageB(1, 1); }
  if (ntk > 1) asm volatile("s_waitcnt vmcnt(4)" ::: "memory");
  else         asm volatile("s_waitcnt vmcnt(0)" ::: "memory");
  BAR();

  for (int t = 0; t < ntk; ++t) {
    const bf16_t* Ar = lds + (t & 1) * 16384 + wr * 8192;
    const bf16_t* Br = lds + 32768 + (t % 3) * 16384 + (wc >> 1) * 8192;
    int bRowOff = (wc & 1) * 64;
    if (t + 1 < ntk) { stageA(t + 1, 0); stageA(t + 1, 1); }
    FENCE();
    bf16x8 bfr[4][2];
#pragma unroll
    for (int n = 0; n < 4; ++n) {
      int R = bRowOff + n * 16 + lr;
#pragma unroll
      for (int ks = 0; ks < 2; ++ks)
        bfr[n][ks] = *(const bf16x8*)(Br + R * 64 + ((ks * 4 + kg) ^ (R & 7)) * 8);
    }
#pragma unroll
    for (int p = 0; p < 4; ++p) {
      bf16x8 afr[2][2];
#pragma unroll
      for (int mm = 0; mm < 2; ++mm) {
        int R = p * 32 + mm * 16 + lr;
#pragma unroll
        for (int ks = 0; ks < 2; ++ks)
          afr[mm][ks] = *(const bf16x8*)(Ar + R * 64 + ((ks * 4 + kg) ^ (R & 7)) * 8);
      }
      if (p == 2 && t + 2 < ntk) stageB(t + 2, 0);
      if (p == 3 && t + 2 < ntk) stageB(t + 2, 1);
      __builtin_amdgcn_s_setprio(1);
#pragma unroll
      for (int mm = 0; mm < 2; ++mm)
#pragma unroll
        for (int n = 0; n < 4; ++n)
#pragma unroll
          for (int ks = 0; ks < 2; ++ks)
            acc[p * 2 + mm][n] =
                __builtin_amdgcn_mfma_f32_16x16x32_bf16(afr[mm][ks], bfr[n][ks],
                                                        acc[p * 2 + mm][n], 0, 0, 0);
      __builtin_amdgcn_s_setprio(0);
    }
    if (t + 2 < ntk)      asm volatile("s_waitcnt vmcnt(4)" ::: "memory");
    else if (t + 1 < ntk) asm volatile("s_waitcnt vmcnt(0)" ::: "memory");
    BAR();
  }
}

// ===== 256Mx128N BK=32 free-running pipe (56KB LDS -> 2 blocks/CU) — used by logits =====
// Element-unit LDS layout: A dbuf 2x8192 elem at [0,16384); B tribuf 3x4096 elem at
// [16384,28672). Per K-tile: A(t+1) staged at top (2 gloads), B(t+2) mid (1 gload);
// end-of-tile counted vmcnt(1) keeps B(t+2) in flight; ONE barrier per tile.
// Ledger: in-flight entering t = {B(t+1)}; issue A(t+1)x2, B(t+2); vmcnt(1) drains
// B(t+1),A(t+1)x2 (FIFO, order pinned by FENCE), leaves B(t+2). Swizzle: 4 col-groups,
// physical = logical ^ (row&3), both-sides (pre-swizzled global src + read XOR).
// 8 waves: wrr=w>>1 (M quarter, 64 rows), wcc=w&1 (N half, 64 cols); acc[4][4]=64 VGPR.
__device__ __forceinline__ void pipe256x128(const bf16_t* __restrict__ Ag,
                                            const bf16_t* __restrict__ Bg,
                                            int K, int ntk, bf16_t* lds, f32x4 acc[4][4]) {
  int tid = threadIdx.x;
  int lane = tid & 63, w = tid >> 6;
  int wrr = w >> 1, wcc = w & 1;
  int lr = lane & 15, kg = lane >> 4;
  int colE = ((lane & 3) ^ ((lane >> 2) & 3)) * 8;  // pre-swizzled global col
  int r0 = w * 16 + (lane >> 2);                    // row in [0,128)

  auto stageA = [&](int t, int h) {  // half h: rows h*128..h*128+127 of the 256-row tile
    const bf16_t* g = Ag + (long)(h * 128 + r0) * K + t * 32 + colE;
    gload_lds16(g, lds + (t & 1) * 8192 + h * 4096 + w * 512);
  };
  auto stageB = [&](int t) {  // 128 N-rows
    const bf16_t* g = Bg + (long)r0 * K + t * 32 + colE;
    gload_lds16(g, lds + 16384 + (t % 3) * 4096 + w * 512);
  };

  stageB(0);
  FENCE();
  stageA(0, 0); stageA(0, 1);
  FENCE();
  if (ntk > 1) stageB(1);
  if (ntk > 1) asm volatile("s_waitcnt vmcnt(1)" ::: "memory");
  else         asm volatile("s_waitcnt vmcnt(0)" ::: "memory");
  BAR();

  for (int t = 0; t < ntk; ++t) {
    const bf16_t* Ar = lds + (t & 1) * 8192;            // rows 0..255 linear, 32 elem/row
    const bf16_t* Br = lds + 16384 + (t % 3) * 4096;    // rows 0..127 linear
    if (t + 1 < ntk) { stageA(t + 1, 0); stageA(t + 1, 1); }
    FENCE();
    bf16x8 bfr[4];
#pragma unroll
    for (int n = 0; n < 4; ++n) {
      int R = wcc * 64 + n * 16 + lr;
      bfr[n] = *(const bf16x8*)(Br + R * 32 + (kg ^ (R & 3)) * 8);
    }
#pragma unroll
    for (int m = 0; m < 4; ++m) {
      int R = wrr * 64 + m * 16 + lr;
      bf16x8 afr = *(const bf16x8*)(Ar + R * 32 + (kg ^ (R & 3)) * 8);
      if (m == 2 && t + 2 < ntk) stageB(t + 2);
      __builtin_amdgcn_s_setprio(1);
#pragma unroll
      for (int n = 0; n < 4; ++n)
        acc[m][n] = __builtin_amdgcn_mfma_f32_16x16x32_bf16(afr, bfr[n], acc[m][n], 0, 0, 0);
      __builtin_amdgcn_s_setprio(0);
    }
    if (t + 2 < ntk)      asm volatile("s_waitcnt vmcnt(1)" ::: "memory");
    else if (t + 1 < ntk) asm volatile("s_waitcnt vmcnt(0)" ::: "memory");
    BAR();
  }
}

// ---------------- casts ----------------
__global__ __launch_bounds__(256) void k_cast(const float* in, bf16_t* out, long n4) {
  long i = (long)blockIdx.x * 256 + threadIdx.x;
  if (i >= n4) return;
  float4 v = ((const float4*)in)[i];
  bf16_t* o = out + i * 4;
  o[0] = (bf16_t)v.x; o[1] = (bf16_t)v.y; o[2] = (bf16_t)v.z; o[3] = (bf16_t)v.w;
}

// two inputs -> contiguous [a|b] bf16 output (a first)
__global__ __launch_bounds__(256) void k_cast2(const float* a, const float* b, bf16_t* out) {
  long i = (long)blockIdx.x * 256 + threadIdx.x;
  const float* src = (i < 1048576) ? a : b;
  long j = (i < 1048576) ? i : i - 1048576;
  float4 v = ((const float4*)src)[j];
  bf16_t* o = out + i * 4;
  o[0] = (bf16_t)v.x; o[1] = (bf16_t)v.y; o[2] = (bf16_t)v.z; o[3] = (bf16_t)v.w;
}

// ------------- merged-LoRA weight transpose -------------
__global__ __launch_bounds__(256) void k_prep_wt(const float* W, const float* A, const float* Bm,
                                                 bf16_t* out, int K, int N,
                                                 long wstride, long astride, long bstride, long ostride) {
  __shared__ float tile[64][65];
  int e = blockIdx.z;
  W += (long)e * wstride;
  out += (long)e * ostride;
  if (A) { A += (long)e * astride; Bm += (long)e * bstride; }
  int k0 = blockIdx.x * 64, n0 = blockIdx.y * 64;
  int tid = threadIdx.x;
  int tn = tid & 63, tk = tid >> 6;
#pragma unroll 4
  for (int i = 0; i < 16; ++i) {
    int k = tk + i * 4;
    float v = W[(long)(k0 + k) * N + (n0 + tn)];
    if (A) {
      const float* Ak = A + (long)(k0 + k) * 4;
      const float* Bn = Bm + n0 + tn;
      v += 0.25f * (Ak[0] * Bn[0] + Ak[1] * Bn[(long)N] + Ak[2] * Bn[2L * N] + Ak[3] * Bn[3L * N]);
    }
    tile[k][tn] = v;
  }
  __syncthreads();
#pragma unroll 4
  for (int i = 0; i < 16; ++i) {
    int n = tk + i * 4;
    out[(long)(n0 + n) * K + (k0 + tn)] = (bf16_t)tile[tn][n];
  }
}

// ---------------- router: softmax gate, top-2, renormalize ----------------
__global__ __launch_bounds__(256) void k_router(const float* x, const float* Wr, float* rw) {
  int w = threadIdx.x >> 6, lane = threadIdx.x & 63;
  long tok = (long)blockIdx.x * 4 + w;
  const float* xr = x + tok * 1024;
  float acc[8] = {0.f, 0.f, 0.f, 0.f, 0.f, 0.f, 0.f, 0.f};
  for (int h = lane; h < 1024; h += 64) {
    float xv = xr[h];
    const float* wr8 = Wr + h * 8;
#pragma unroll
    for (int e = 0; e < 8; ++e) acc[e] += xv * wr8[e];
  }
#pragma unroll
  for (int o = 32; o; o >>= 1)
#pragma unroll
    for (int e = 0; e < 8; ++e) acc[e] += __shfl_xor(acc[e], o);
  if (lane == 0) {
    int i1 = 0;
    for (int e = 1; e < 8; ++e) if (acc[e] > acc[i1]) i1 = e;
    int i2 = (i1 == 0) ? 1 : 0;
    for (int e = 0; e < 8; ++e) { if (e == i1) continue; if (acc[e] > acc[i2]) i2 = e; }
    float g2 = expf(acc[i2] - acc[i1]);
    float d = 1.f / (1.f + g2);
    float* dst = rw + tok * 8;
#pragma unroll
    for (int e = 0; e < 8; ++e) dst[e] = (e == i1) ? d : ((e == i2) ? g2 * d : 0.f);
  }
}

// -------- MoE schedule: per-expert token lists (order-free, output-deterministic) --------
__global__ __launch_bounds__(256) void k_sched(const float* rw, int* eidx, float* ewgt, int* tcnt) {
  int e = blockIdx.x, tid = threadIdx.x;
  __shared__ int cnt;
  if (tid == 0) cnt = 0;
  __syncthreads();
  for (int t = tid; t < 4096; t += 256) {
    const float* r = rw + (long)t * 8;
    float wv = r[e];
    if (wv > 0.f) {
      int slot = 0;
      for (int j = 0; j < 8; ++j) if (j < e && r[j] > 0.f) slot = 1;
      int p = atomicAdd(&cnt, 1);
      eidx[e * 4096 + p] = t * 2 + slot;
      ewgt[e * 4096 + p] = wv;
    }
  }
  __syncthreads();
  int c = cnt;
  int padded = (c + 127) & ~127;
  for (int p = c + tid; p < padded; p += 256) eidx[e * 4096 + p] = -1;
  if (tid == 0) tcnt[e] = padded >> 7;  // tiles of 128 rows
}

// -------- gathered-A 128^2 MoE GEMM: Yp[slot][tok] = w * (x[tok] @ We^T + cbc_e) --------
__global__ __launch_bounds__(256) void k_moe128(const bf16_t* x_bf, const bf16_t* wexp_t,
                                                const int* eidx, const float* ewgt,
                                                const int* tcnt, const float* cbc, float* Yp) {
  int e = 0, ti = blockIdx.y;
  while (e < 8 && ti >= tcnt[e]) { ti -= tcnt[e]; ++e; }
  if (e >= 8) return;
  const int* idx = eidx + e * 4096 + ti * 128;
  const float* wgt = ewgt + e * 4096 + ti * 128;
  __shared__ bf16_t As[4096] __attribute__((aligned(16)));
  __shared__ bf16_t Bs[4096] __attribute__((aligned(16)));
  int tid = threadIdx.x, lane = tid & 63, w = tid >> 6;
  const bf16_t* aP[2];
#pragma unroll
  for (int r = 0; r < 2; ++r) {
    int row = r * 64 + w * 16 + (lane >> 2);
    int v = idx[row];
    int tok = (v < 0) ? 0 : (v >> 1);
    aP[r] = x_bf + (long)tok * 1024 + (lane & 3) * 8;
  }
  const bf16_t* Bb = wexp_t + (long)e * 1048576 + (long)blockIdx.x * 131072;
  int wr = w >> 1, wc = w & 1, lr = lane & 15, kg = lane >> 4;
  f32x4 acc[4][4];
  zero_acc(acc);
  for (int kt = 0; kt < 1024; kt += 32) {
    __syncthreads();
    gload_lds16(aP[0] + kt, As + (w * 16) * 32);
    gload_lds16(aP[1] + kt, As + (64 + w * 16) * 32);
    stage_tile(Bb + kt, 1024, Bs, tid);
    __syncthreads();
    bf16x8 a[4], b[4];
#pragma unroll
    for (int m = 0; m < 4; ++m)
      a[m] = *(const bf16x8*)&As[(wr * 64 + m * 16 + lr) * 32 + kg * 8];
#pragma unroll
    for (int n = 0; n < 4; ++n)
      b[n] = *(const bf16x8*)&Bs[(wc * 64 + n * 16 + lr) * 32 + kg * 8];
#pragma unroll
    for (int m = 0; m < 4; ++m)
#pragma unroll
      for (int n = 0; n < 4; ++n)
        acc[m][n] = __builtin_amdgcn_mfma_f32_16x16x32_bf16(a[m], b[n], acc[m][n], 0, 0, 0);
  }
  const float* cb = cbc + e * 1024 + blockIdx.x * 128;
#pragma unroll
  for (int m = 0; m < 4; ++m)
#pragma unroll
    for (int r = 0; r < 4; ++r) {
      int lrow = wr * 64 + m * 16 + kg * 4 + r;
      int v = idx[lrow];
      if (v < 0) continue;
      int tok = v >> 1, slot = v & 1;
      float wg = wgt[lrow];
      float* op = Yp + ((long)slot * 4096 + tok) * 1024 + blockIdx.x * 128;
#pragma unroll
      for (int n = 0; n < 4; ++n) {
        int gc = wc * 64 + n * 16 + lr;
        op[gc] = wg * (acc[m][n][r] + cb[gc]);
      }
    }
}

// ------------- combine the two expert slots -> bf16 -------------
__global__ __launch_bounds__(256) void k_combine2(const float* Yp, bf16_t* out) {
  long t = blockIdx.x;
  int d = threadIdx.x * 4;
  f32x4 a = *(const f32x4*)(Yp + t * 1024 + d);
  f32x4 b = *(const f32x4*)(Yp + 4194304L + t * 1024 + d);
  bf16x4 r;
#pragma unroll
  for (int i = 0; i < 4; ++i) r[i] = (bf16_t)(a[i] + b[i]);
  *(bf16x4*)(out + t * 1024 + d) = r;
}

// -------- batched bf16-out 128^2 GEMM with per-z f32 bias (q & k projections) --------
__global__ __launch_bounds__(256) void k_gemm_bias_bf16(const bf16_t* A, long Az,
                                                        const bf16_t* Bt, long Bz,
                                                        const float* bias0, const float* bias1,
                                                        bf16_t* out, long Oz, int K, int ldc) {
  __shared__ bf16_t As[4096] __attribute__((aligned(16)));
  __shared__ bf16_t Bs[4096] __attribute__((aligned(16)));
  int z = blockIdx.z;
  A += (long)z * Az; Bt += (long)z * Bz; out += (long)z * Oz;
  const float* bias = z ? bias1 : bias0;
  int rowBase = blockIdx.x * 128, colBase = blockIdx.y * 128;
  f32x4 acc[4][4];
  zero_acc(acc);
  gemm_core(A, Bt, K, K, K, rowBase, colBase, As, Bs, acc);
  int tid = threadIdx.x, lane = tid & 63, w = tid >> 6;
  int wr = w >> 1, wc = w & 1, lc = lane & 15, kg = lane >> 4;
#pragma unroll
  for (int m = 0; m < 4; ++m)
#pragma unroll
    for (int n = 0; n < 4; ++n)
#pragma unroll
      for (int r = 0; r < 4; ++r) {
        int gr = rowBase + wr * 64 + m * 16 + kg * 4 + r;
        int gc = colBase + wc * 64 + n * 16 + lc;
        out[(long)gr * ldc + gc] = (bf16_t)(acc[m][n][r] + bias[gc]);
      }
}

// ------------- 128^2 f32-out GEMM (QK^T) -------------
template <bool NT>
__global__ __launch_bounds__(256) void k_gemm128(
    const bf16_t* __restrict__ A, long Az, const bf16_t* __restrict__ Bt, long Bz,
    const float* __restrict__ bias, float* __restrict__ out, long Oz,
    int mB, int N, int K, float scale) {
  __shared__ bf16_t As[4096] __attribute__((aligned(16)));
  __shared__ bf16_t Bs[4096] __attribute__((aligned(16)));
  __shared__ float fl[32 * 132];
  int tid = threadIdx.x;
  A += (long)blockIdx.y * Az;
  Bt += (long)blockIdx.y * Bz;
  out += (long)blockIdx.y * Oz;
  int per = gridDim.x >> 3;
  int bid = blockIdx.x;
  int swz = (bid & 7) * per + (bid >> 3);
  int rowB = swz % mB, colB = swz / mB;
  int rowBase = rowB << 7, colBase = colB << 7;
  f32x4 acc[4][4];
  zero_acc(acc);
  gemm_core(A, Bt, K, K, K, rowBase, colBase, As, Bs, acc);
  int lane = tid & 63, w = tid >> 6;
  int wr = w >> 1, wc = w & 1, lc = lane & 15, kg = lane >> 4;
  int colq = (tid & 31) * 4;
  f32x4 bb = {0.f, 0.f, 0.f, 0.f};
  if (bias) bb = *(const f32x4*)(bias + colBase + colq);
#pragma unroll
  for (int c = 0; c < 4; ++c) {
    __syncthreads();
    if (wr == (c >> 1)) {
      int m0 = (c & 1) * 2;
#pragma unroll
      for (int mm = 0; mm < 2; ++mm)
#pragma unroll
        for (int n = 0; n < 4; ++n)
#pragma unroll
          for (int r = 0; r < 4; ++r)
            fl[(mm * 16 + kg * 4 + r) * 132 + wc * 64 + n * 16 + lc] = acc[m0 + mm][n][r] * scale;
    }
    __syncthreads();
    long grow = rowBase + c * 32;
#pragma unroll
    for (int q = 0; q < 4; ++q) {
      int idx = q * 256 + tid;
      int row = idx >> 5;
      f32x4 v = *(const f32x4*)&fl[row * 132 + colq];
      v += bb;
      float* op = out + (grow + row) * (long)N + colBase + colq;
      if (NT) __builtin_nontemporal_store(v, (f32x4*)op);
      else *(f32x4*)op = v;
    }
  }
}

// ------------- 256Mx128N BK=32 deep-pipelined GEMM, f32 out (logits, 2 blocks/CU) -------------
template <bool NT>
__global__ __launch_bounds__(512, 4) void k_gemm256(
    const bf16_t* __restrict__ A, long Az, const bf16_t* __restrict__ Bt, long Bz,
    const float* __restrict__ bias, float* __restrict__ out, long Oz,
    int mBlocks, int N, int K, int ntk, float scale) {
  __shared__ bf16_t lds[28672] __attribute__((aligned(16)));  // 56 KB
  int tid = threadIdx.x;
  int lane = tid & 63, w = tid >> 6;
  int wrr = w >> 1, wcc = w & 1;
  int lr = lane & 15, kg = lane >> 4;
  A += (long)blockIdx.y * Az;
  Bt += (long)blockIdx.y * Bz;
  out += (long)blockIdx.y * Oz;
  int per = gridDim.x >> 3;
  int bid = blockIdx.x;
  int swz = (bid & 7) * per + (bid >> 3);
  int rowB = swz % mBlocks, colB = swz / mBlocks;
  long rowBase = (long)rowB << 8, colBase = (long)colB << 7;

  f32x4 acc[4][4];
  zero_acc(acc);
  pipe256x128(A + rowBase * K, Bt + colBase * K, K, ntk, lds, acc);

  // epilogue: 4 chunks of 64 rows through LDS (f32, stride 132) -> 512B-contiguous stores
  float* fl = (float*)lds;
  int colq = (tid & 31) * 4;
  f32x4 bb = {0.f, 0.f, 0.f, 0.f};
  if (bias) bb = *(const f32x4*)(bias + colBase + colq);
#pragma unroll
  for (int c = 0; c < 4; ++c) {
    if (wrr == c) {
#pragma unroll
      for (int m = 0; m < 4; ++m)
#pragma unroll
        for (int n = 0; n < 4; ++n)
#pragma unroll
          for (int rr = 0; rr < 4; ++rr)
            fl[(m * 16 + kg * 4 + rr) * 132 + wcc * 64 + n * 16 + lr] = acc[m][n][rr] * scale;
    }
    BAR();
    long grow = rowBase + c * 64;
#pragma unroll
    for (int q = 0; q < 4; ++q) {
      int idx = q * 512 + tid;
      int row = idx >> 5;
      f32x4 v = *(const f32x4*)&fl[row * 132 + colq];
      v += bb;
      float* op = out + (grow + row) * (long)N + colBase + colq;
      if (NT) __builtin_nontemporal_store(v, (f32x4*)op);
      else *(f32x4*)op = v;
    }
    BAR();
  }
}

// ------------- 256^2 cache compressor: gelu + sigmoid-gated masked column-sum -------------
__global__ __launch_bounds__(512, 2) void k_cache256(
    const bf16_t* __restrict__ cache_bf, const bf16_t* __restrict__ wd_t,
    const float* __restrict__ ci, float* __restrict__ partial) {
  __shared__ bf16_t lds[81920] __attribute__((aligned(16)));
  int tid = threadIdx.x;
  int lane = tid & 63, w = tid >> 6;
  int wr = w >> 2, wc = w & 3;
  int lr = lane & 15, kg = lane >> 4;
  int e = blockIdx.y;
  const bf16_t* A = cache_bf + (long)e * 4194304;
  const bf16_t* Bt = wd_t + (long)e * 524288;
  int per = gridDim.x >> 3;
  int bid = blockIdx.x;
  int swz = (bid & 7) * per + (bid >> 3);
  int rowB = swz % 16, colB = swz / 16;
  long rowBase = (long)rowB << 8, colBase = (long)colB << 8;

  f32x4 acc[8][4];
#pragma unroll
  for (int m = 0; m < 8; ++m)
#pragma unroll
    for (int n = 0; n < 4; ++n)
#pragma unroll
      for (int i = 0; i < 4; ++i) acc[m][n][i] = 0.f;
  pipe256(A + rowBase * 1024, Bt + colBase * 1024, 1024, 16, lds, acc);

  float* colsum = (float*)lds;
  if (tid < 256) colsum[tid] = 0.f;
  __syncthreads();
  int csize = 4096 - 256 * e;
  const float* cie = ci + (long)e * 4096;
  float s[4] = {0.f, 0.f, 0.f, 0.f};
#pragma unroll
  for (int mg = 0; mg < 8; ++mg)
#pragma unroll
    for (int rr = 0; rr < 4; ++rr) {
      int row = (int)rowBase + wr * 128 + mg * 16 + kg * 4 + rr;
      float wf = (row < csize) ? 1.f / (1.f + expf(-cie[row])) : 0.f;
#pragma unroll
      for (int n = 0; n < 4; ++n) {
        float xv = acc[mg][n][rr];
        float t = xv + 0.044715f * xv * xv * xv;
        float gl = 0.5f * xv * (1.f + tanhf(0.7978845608028654f * t));
        s[n] += gl * wf;
      }
    }
#pragma unroll
  for (int n = 0; n < 4; ++n)
    atomicAdd(&colsum[wc * 64 + n * 16 + lr], s[n]);
  __syncthreads();
  if (tid < 256)
    partial[((long)e * 16 + rowB) * 512 + colB * 256 + tid] = colsum[tid];
}

// ------------- cached values: (fused reduce +) Wu matvec -> LoRA finalize -------------
__global__ __launch_bounds__(256) void k_wu_mv(const float* partial, const float* Wu, float* pre) {
  int e = blockIdx.x;
  int d = blockIdx.y * 256 + threadIdx.x;
  __shared__ float gs[512];
  for (int j = threadIdx.x; j < 512; j += 256) {
    float s = 0.f;
    for (int mx = 0; mx < 16; ++mx) s += partial[((long)e * 16 + mx) * 512 + j];
    gs[j] = s;
  }
  __syncthreads();
  const float* W = Wu + (long)e * 524288 + d;
  float s = 0.f;
  for (int j = 0; j < 512; ++j) s += gs[j] * W[(long)j * 1024];
  pre[e * 1024 + d] = s;
}

__global__ __launch_bounds__(256) void k_cached_fin(const float* pre, const float* Av,
                                                    const float* Bv, const float* bexp,
                                                    float* cbc) {
  int e = blockIdx.x, tid = threadIdx.x;
  __shared__ float ps[1024];
  __shared__ float tt[4];
  for (int d = tid; d < 1024; d += 256) ps[d] = pre[e * 1024 + d];
  __syncthreads();
  int w = tid >> 6, lane = tid & 63;
  {
    float s = 0.f;
    const float* Ave = Av + e * 4096;
    for (int d = lane; d < 1024; d += 64) s += ps[d] * Ave[d * 4 + w];
#pragma unroll
    for (int o = 32; o; o >>= 1) s += __shfl_xor(s, o);
    if (lane == 0) tt[w] = s;
  }
  __syncthreads();
  float inv = 1.f / (float)(4096 - 256 * e);
  const float* Bve = Bv + e * 4096;
  for (int d = tid; d < 1024; d += 256) {
    float lora = tt[0] * Bve[d] + tt[1] * Bve[1024 + d] + tt[2] * Bve[2048 + d] + tt[3] * Bve[3072 + d];
    cbc[e * 1024 + d] = (ps[d] + 0.25f * lora) * inv + bexp[e * 1024 + d];
  }
}

// ------------- attention row stats (single-pass online) + column sums -------------
__global__ __launch_bounds__(256) void k_rowstat(const float* S, float* mrow, float* zinv) {
  long row = blockIdx.x;
  const float* r = S + row * 2048;
  int tid = threadIdx.x;
  float m = -3.4e38f, s = 0.f;
  for (int c = tid; c < 2048; c += 256) {
    float v = r[c];
    if (v > m) { s = s * expf(m - v) + 1.f; m = v; }
    else s += expf(v - m);
  }
#pragma unroll
  for (int o = 32; o; o >>= 1) {
    float mo = __shfl_xor(m, o), so = __shfl_xor(s, o);
    float M = fmaxf(m, mo);
    s = s * expf(m - M) + so * expf(mo - M);
    m = M;
  }
  __shared__ float sm[4], ss[4];
  if ((tid & 63) == 0) { sm[tid >> 6] = m; ss[tid >> 6] = s; }
  __syncthreads();
  if (tid == 0) {
    float M = fmaxf(fmaxf(sm[0], sm[1]), fmaxf(sm[2], sm[3]));
    float S2 = ss[0] * expf(sm[0] - M) + ss[1] * expf(sm[1] - M) +
               ss[2] * expf(sm[2] - M) + ss[3] * expf(sm[3] - M);
    mrow[row] = M;
    zinv[row] = 1.f / S2;
  }
}

__global__ __launch_bounds__(256) void k_imp_part(const float* S, const float* mrow, const float* zinv,
                                                  float* ipart) {
  int k = blockIdx.x * 256 + threadIdx.x;
  int qc = blockIdx.y, b = blockIdx.z;
  const float* Sb = S + (long)b * 4194304;
  const float* mb = mrow + b * 2048;
  const float* zb = zinv + b * 2048;
  float s = 0.f;
  int q0 = qc * 128;
  for (int q = q0; q < q0 + 128; ++q)
    s += expf(Sb[(long)q * 2048 + k] - mb[q]) * zb[q];
  ipart[((long)b * 16 + qc) * 2048 + k] = s;
}

__global__ __launch_bounds__(256) void k_imp_fin(const float* ipart, float* out) {
  int k = blockIdx.x * 256 + threadIdx.x;
  int b = blockIdx.y;
  float s = 0.f;
  for (int qc = 0; qc < 16; ++qc) s += ipart[((long)b * 16 + qc) * 2048 + k];
  out[b * 2048 + k] = s;
}

extern "C" void kernel_launch(void* const* d_in, const int* in_sizes, int n_in,
                              void* d_out, int out_size, void* d_ws, size_t ws_size,
                              hipStream_t stream) {
  (void)in_sizes; (void)n_in; (void)out_size; (void)ws_size;
  const float* x    = (const float*)d_in[0];
  const float* query= (const float*)d_in[1];
  const float* cach = (const float*)d_in[2];
  const float* ci   = (const float*)d_in[3];
  const float* Wr   = (const float*)d_in[4];
  const float* Wexp = (const float*)d_in[5];
  const float* bexp = (const float*)d_in[6];
  const float* Aexp = (const float*)d_in[7];
  const float* Bexp = (const float*)d_in[8];
  const float* Wq   = (const float*)d_in[9];
  const float* bq   = (const float*)d_in[10];
  const float* Wk   = (const float*)d_in[11];
  const float* bk   = (const float*)d_in[12];
  const float* Aq   = (const float*)d_in[13];
  const float* Bq   = (const float*)d_in[14];
  const float* Ak   = (const float*)d_in[15];
  const float* Bk   = (const float*)d_in[16];
  const float* Wd   = (const float*)d_in[17];
  const float* Wu   = (const float*)d_in[18];
  const float* Av   = (const float*)d_in[19];
  const float* Bv   = (const float*)d_in[20];
  const float* Wv   = (const float*)d_in[21];
  const float* bv   = (const float*)d_in[22];
  float* out = (float*)d_out;

  size_t off = 0;
  char* base = (char*)d_ws;
  auto carve = [&](size_t bytes) { char* p = base + off; off = (off + bytes + 255) & ~(size_t)255; return (void*)p; };
  bf16_t* query_bf = (bf16_t*)carve(8388608);
  bf16_t* x_bf     = (bf16_t*)carve(8388608);   // = query_bf + 4194304 (contiguous for k_cast2)
  bf16_t* q_bf     = (bf16_t*)carve(8388608);
  bf16_t* k_bf     = (bf16_t*)carve(8388608);   // = q_bf + 4194304
  bf16_t* expert_bf= (bf16_t*)carve(8388608);
  bf16_t* wq_t     = (bf16_t*)carve(2097152);
  bf16_t* wk_t     = (bf16_t*)carve(2097152);   // = wq_t + 1048576
  bf16_t* wd_t     = (bf16_t*)carve(8388608);
  bf16_t* wexp_t   = (bf16_t*)carve(16777216);
  float*  s_att    = (float*)carve(33554432);
  float*  mrow     = (float*)carve(16384);
  float*  zinv     = (float*)carve(16384);
  float*  rw       = (float*)carve(131072);
  float*  partial  = (float*)carve(262144);
  float*  pre      = (float*)carve(32768);
  float*  cbc      = (float*)carve(32768);
  float*  ipart    = (float*)carve(262144);
  int*    eidx     = (int*)carve(131072);
  float*  ewgt     = (float*)carve(131072);
  int*    tcnt     = (int*)carve(256);
  // uni region time-shares (stream-ordered): cache_bf -> Yp (MoE outputs) -> wv_t
  void*   uni      = carve(71303168);  // 68 MB
  bf16_t* cache_bf = (bf16_t*)uni;
  float*  Yp       = (float*)uni;      // 2 x 4096 x 1024 f32 = 33.5 MB
  bf16_t* wv_t     = (bf16_t*)uni;

  // casts
  k_cast2<<<8192, 256, 0, stream>>>(query, x, query_bf);
  k_cast<<<32768, 256, 0, stream>>>(cach, cache_bf, 8388608);
  // merged-LoRA transposed weights
  k_prep_wt<<<dim3(16, 16, 1), 256, 0, stream>>>(Wq, Aq, Bq, wq_t, 1024, 1024, 0, 0, 0, 0);
  k_prep_wt<<<dim3(16, 16, 1), 256, 0, stream>>>(Wk, Ak, Bk, wk_t, 1024, 1024, 0, 0, 0, 0);
  k_prep_wt<<<dim3(16, 8, 8), 256, 0, stream>>>(Wd, nullptr, nullptr, wd_t, 1024, 512, 524288, 0, 0, 524288);
  k_prep_wt<<<dim3(16, 16, 8), 256, 0, stream>>>(Wexp, Aexp, Bexp, wexp_t, 1024, 1024, 1048576, 4096, 4096, 1048576);
  // router + MoE schedule
  k_router<<<1024, 256, 0, stream>>>(x, Wr, rw);
  k_sched<<<8, 256, 0, stream>>>(rw, eidx, ewgt, tcnt);
  // q & k projections in one batched launch
  k_gemm_bias_bf16<<<dim3(32, 8, 2), 256, 0, stream>>>(query_bf, 4194304, wq_t, 1048576,
                                                       bq, bk, q_bf, 4194304, 1024, 1024);
  // attention scores + importance
  k_gemm128<false><<<dim3(256, 2), 256, 0, stream>>>(q_bf, 2097152, k_bf, 2097152, nullptr,
                                                     s_att, 4194304, 16, 2048, 1024, 0.03125f);
  k_rowstat<<<4096, 256, 0, stream>>>(s_att, mrow, zinv);
  k_imp_part<<<dim3(8, 16, 2), 256, 0, stream>>>(s_att, mrow, zinv, ipart);
  k_imp_fin<<<dim3(8, 2), 256, 0, stream>>>(ipart, out + 131072000L);
  // cache compressor -> cached values
  k_cache256<<<dim3(32, 8), 512, 0, stream>>>(cache_bf, wd_t, ci, partial);
  k_wu_mv<<<dim3(8, 4), 256, 0, stream>>>(partial, Wu, pre);
  k_cached_fin<<<8, 256, 0, stream>>>(pre, Av, Bv, bexp, cbc);
  // top-2 gather-GEMM (writes Yp over cache_bf region; cache256 already consumed it)
  k_moe128<<<dim3(8, 72), 256, 0, stream>>>(x_bf, wexp_t, eidx, ewgt, tcnt, cbc, Yp);
  k_combine2<<<4096, 256, 0, stream>>>(Yp, expert_bf);
  // vocab projection: 256Mx128N BK=32 pipe, 2 blocks/CU, NT f32 out
  k_prep_wt<<<dim3(16, 500, 1), 256, 0, stream>>>(Wv, nullptr, nullptr, wv_t, 1024, 32000, 0, 0, 0, 0);
  k_gemm256<true><<<dim3(4000, 1), 512, 0, stream>>>(expert_bf, 0, wv_t, 0, bv,
                                                     out, 0, 16, 32000, 1024, 32, 1.0f);
}

// Round 14
// 737.707 us; speedup vs baseline: 1.0413x; 1.0413x over previous
//
#include <hip/hip_runtime.h>

typedef __bf16 bf16_t;
typedef __bf16 bf16x4 __attribute__((ext_vector_type(4)));
typedef __bf16 bf16x8 __attribute__((ext_vector_type(8)));
typedef float f32x4 __attribute__((ext_vector_type(4)));

#define AS1 __attribute__((address_space(1)))
#define AS3 __attribute__((address_space(3)))
#define BAR() asm volatile("s_barrier" ::: "memory")
// pin VMEM/DS-write issue order; ALU/VALU/SALU/MFMA/DS_READ may cross
#define FENCE() __builtin_amdgcn_sched_barrier(0x10F)

__device__ __forceinline__ void gload_lds16(const void* g, void* l) {
  __builtin_amdgcn_global_load_lds((AS1 void*)g, (AS3 void*)l, 16, 0, 0);
}

// Stage a [128 rows x 32 cols] bf16 tile from row-major global (ld elems/row) into
// linear LDS [128][32]. 256 threads, 2 rounds of global_load_lds width-16.
__device__ __forceinline__ void stage_tile(const bf16_t* g, int ld, bf16_t* lds, int tid) {
  int w = tid >> 6, lane = tid & 63;
#pragma unroll
  for (int r = 0; r < 2; ++r) {
    int rowbase = r * 64 + w * 16;
    const bf16_t* gp = g + (long)(rowbase + (lane >> 2)) * ld + (lane & 3) * 8;
    bf16_t* lp = lds + rowbase * 32;  // wave-uniform; HW adds lane*16B
    gload_lds16(gp, lp);
  }
}

// C[128,128] tile of A[M,K] (rm) x Bt[N,K] (rm), 4 waves 2x2, 16x16x32 MFMA.
__device__ __forceinline__ void gemm_core(const bf16_t* A, const bf16_t* Bt, int lda, int ldb,
                                          int K, int rowBase, int colBase,
                                          bf16_t* As, bf16_t* Bs, f32x4 acc[4][4]) {
  int tid = threadIdx.x;
  int lane = tid & 63, w = tid >> 6;
  int wr = w >> 1, wc = w & 1;
  int lr = lane & 15, kg = lane >> 4;
  const bf16_t* Ab = A + (long)rowBase * lda;
  const bf16_t* Bb = Bt + (long)colBase * ldb;
  for (int kt = 0; kt < K; kt += 32) {
    __syncthreads();
    stage_tile(Ab + kt, lda, As, tid);
    stage_tile(Bb + kt, ldb, Bs, tid);
    __syncthreads();
    bf16x8 a[4], b[4];
#pragma unroll
    for (int m = 0; m < 4; ++m)
      a[m] = *(const bf16x8*)&As[(wr * 64 + m * 16 + lr) * 32 + kg * 8];
#pragma unroll
    for (int n = 0; n < 4; ++n)
      b[n] = *(const bf16x8*)&Bs[(wc * 64 + n * 16 + lr) * 32 + kg * 8];
#pragma unroll
    for (int m = 0; m < 4; ++m)
#pragma unroll
      for (int n = 0; n < 4; ++n)
        acc[m][n] = __builtin_amdgcn_mfma_f32_16x16x32_bf16(a[m], b[n], acc[m][n], 0, 0, 0);
  }
}

__device__ __forceinline__ void zero_acc(f32x4 acc[4][4]) {
#pragma unroll
  for (int m = 0; m < 4; ++m)
#pragma unroll
    for (int n = 0; n < 4; ++n)
#pragma unroll
      for (int i = 0; i < 4; ++i) acc[m][n][i] = 0.f;
}

// ===== 256x256 BK=64 free-running pipe (160KB LDS, 1 block/CU) =====
// Per K-tile: A(t+1) staged at top, B(t+2) mid-tile, compiler-scheduled ds_read/MFMA
// interleave (no intra-tile barriers/lgkm waits), setprio around MFMA clusters,
// counted vmcnt(4) + ONE s_barrier per tile. Measured best logits structure (R10).
__device__ __forceinline__ void pipe256(const bf16_t* __restrict__ Ag,
                                        const bf16_t* __restrict__ Bg,
                                        int K, int ntk, bf16_t* lds, f32x4 acc[8][4]) {
  int tid = threadIdx.x;
  int lane = tid & 63, w = tid >> 6;
  int wr = w >> 2, wc = w & 3;
  int lr = lane & 15, kg = lane >> 4;
  int colE = ((lane & 7) ^ (lane >> 3)) * 8;  // pre-swizzled global col (rule #21)
  int r0 = w * 16 + (lane >> 3);

  auto stageA = [&](int t, int h) {
    const bf16_t* g = Ag + (long)(h * 128 + r0) * K + t * 64 + colE;
    bf16_t* l = lds + (t & 1) * 16384 + h * 8192 + w * 1024;
    gload_lds16(g, l);
    gload_lds16(g + (long)8 * K, l + 512);
  };
  auto stageB = [&](int t, int h) {
    const bf16_t* g = Bg + (long)(h * 128 + r0) * K + t * 64 + colE;
    bf16_t* l = lds + 32768 + (t % 3) * 16384 + h * 8192 + w * 1024;
    gload_lds16(g, l);
    gload_lds16(g + (long)8 * K, l + 512);
  };

  stageB(0, 0); stageB(0, 1);
  FENCE();
  stageA(0, 0); stageA(0, 1);
  FENCE();
  if (ntk > 1) { stageB(1, 0); stageB(1, 1); }
  if (ntk > 1) asm volatile("s_waitcnt vmcnt(4)" ::: "memory");
  else         asm volatile("s_waitcnt vmcnt(0)" ::: "memory");
  BAR();

  for (int t = 0; t < ntk; ++t) {
    const bf16_t* Ar = lds + (t & 1) * 16384 + wr * 8192;
    const bf16_t* Br = lds + 32768 + (t % 3) * 16384 + (wc >> 1) * 8192;
    int bRowOff = (wc & 1) * 64;
    if (t + 1 < ntk) { stageA(t + 1, 0); stageA(t + 1, 1); }
    FENCE();
    bf16x8 bfr[4][2];
#pragma unroll
    for (int n = 0; n < 4; ++n) {
      int R = bRowOff + n * 16 + lr;
#pragma unroll
      for (int ks = 0; ks < 2; ++ks)
        bfr[n][ks] = *(const bf16x8*)(Br + R * 64 + ((ks * 4 + kg) ^ (R & 7)) * 8);
    }
#pragma unroll
    for (int p = 0; p < 4; ++p) {
      bf16x8 afr[2][2];
#pragma unroll
      for (int mm = 0; mm < 2; ++mm) {
        int R = p * 32 + mm * 16 + lr;
#pragma unroll
        for (int ks = 0; ks < 2; ++ks)
          afr[mm][ks] = *(const bf16x8*)(Ar + R * 64 + ((ks * 4 + kg) ^ (R & 7)) * 8);
      }
      if (p == 2 && t + 2 < ntk) stageB(t + 2, 0);
      if (p == 3 && t + 2 < ntk) stageB(t + 2, 1);
      __builtin_amdgcn_s_setprio(1);
#pragma unroll
      for (int mm = 0; mm < 2; ++mm)
#pragma unroll
        for (int n = 0; n < 4; ++n)
#pragma unroll
          for (int ks = 0; ks < 2; ++ks)
            acc[p * 2 + mm][n] =
                __builtin_amdgcn_mfma_f32_16x16x32_bf16(afr[mm][ks], bfr[n][ks],
                                                        acc[p * 2 + mm][n], 0, 0, 0);
      __builtin_amdgcn_s_setprio(0);
    }
    if (t + 2 < ntk)      asm volatile("s_waitcnt vmcnt(4)" ::: "memory");
    else if (t + 1 < ntk) asm volatile("s_waitcnt vmcnt(0)" ::: "memory");
    BAR();
  }
}

// ---------------- casts ----------------
__global__ __launch_bounds__(256) void k_cast(const float* in, bf16_t* out, long n4) {
  long i = (long)blockIdx.x * 256 + threadIdx.x;
  if (i >= n4) return;
  float4 v = ((const float4*)in)[i];
  bf16_t* o = out + i * 4;
  o[0] = (bf16_t)v.x; o[1] = (bf16_t)v.y; o[2] = (bf16_t)v.z; o[3] = (bf16_t)v.w;
}

// two inputs -> contiguous [a|b] bf16 output (a first)
__global__ __launch_bounds__(256) void k_cast2(const float* a, const float* b, bf16_t* out) {
  long i = (long)blockIdx.x * 256 + threadIdx.x;
  const float* src = (i < 1048576) ? a : b;
  long j = (i < 1048576) ? i : i - 1048576;
  float4 v = ((const float4*)src)[j];
  bf16_t* o = out + i * 4;
  o[0] = (bf16_t)v.x; o[1] = (bf16_t)v.y; o[2] = (bf16_t)v.z; o[3] = (bf16_t)v.w;
}

// ------------- merged-LoRA weight transpose -------------
__global__ __launch_bounds__(256) void k_prep_wt(const float* W, const float* A, const float* Bm,
                                                 bf16_t* out, int K, int N,
                                                 long wstride, long astride, long bstride, long ostride) {
  __shared__ float tile[64][65];
  int e = blockIdx.z;
  W += (long)e * wstride;
  out += (long)e * ostride;
  if (A) { A += (long)e * astride; Bm += (long)e * bstride; }
  int k0 = blockIdx.x * 64, n0 = blockIdx.y * 64;
  int tid = threadIdx.x;
  int tn = tid & 63, tk = tid >> 6;
#pragma unroll 4
  for (int i = 0; i < 16; ++i) {
    int k = tk + i * 4;
    float v = W[(long)(k0 + k) * N + (n0 + tn)];
    if (A) {
      const float* Ak = A + (long)(k0 + k) * 4;
      const float* Bn = Bm + n0 + tn;
      v += 0.25f * (Ak[0] * Bn[0] + Ak[1] * Bn[(long)N] + Ak[2] * Bn[2L * N] + Ak[3] * Bn[3L * N]);
    }
    tile[k][tn] = v;
  }
  __syncthreads();
#pragma unroll 4
  for (int i = 0; i < 16; ++i) {
    int n = tk + i * 4;
    out[(long)(n0 + n) * K + (k0 + tn)] = (bf16_t)tile[tn][n];
  }
}

// ---------------- router: softmax gate, top-2, renormalize ----------------
__global__ __launch_bounds__(256) void k_router(const float* x, const float* Wr, float* rw) {
  int w = threadIdx.x >> 6, lane = threadIdx.x & 63;
  long tok = (long)blockIdx.x * 4 + w;
  const float* xr = x + tok * 1024;
  float acc[8] = {0.f, 0.f, 0.f, 0.f, 0.f, 0.f, 0.f, 0.f};
  for (int h = lane; h < 1024; h += 64) {
    float xv = xr[h];
    const float* wr8 = Wr + h * 8;
#pragma unroll
    for (int e = 0; e < 8; ++e) acc[e] += xv * wr8[e];
  }
#pragma unroll
  for (int o = 32; o; o >>= 1)
#pragma unroll
    for (int e = 0; e < 8; ++e) acc[e] += __shfl_xor(acc[e], o);
  if (lane == 0) {
    int i1 = 0;
    for (int e = 1; e < 8; ++e) if (acc[e] > acc[i1]) i1 = e;
    int i2 = (i1 == 0) ? 1 : 0;
    for (int e = 0; e < 8; ++e) { if (e == i1) continue; if (acc[e] > acc[i2]) i2 = e; }
    float g2 = expf(acc[i2] - acc[i1]);
    float d = 1.f / (1.f + g2);
    float* dst = rw + tok * 8;
#pragma unroll
    for (int e = 0; e < 8; ++e) dst[e] = (e == i1) ? d : ((e == i2) ? g2 * d : 0.f);
  }
}

// -------- MoE schedule: per-expert token lists (order-free, output-deterministic) --------
__global__ __launch_bounds__(256) void k_sched(const float* rw, int* eidx, float* ewgt, int* tcnt) {
  int e = blockIdx.x, tid = threadIdx.x;
  __shared__ int cnt;
  if (tid == 0) cnt = 0;
  __syncthreads();
  for (int t = tid; t < 4096; t += 256) {
    const float* r = rw + (long)t * 8;
    float wv = r[e];
    if (wv > 0.f) {
      int slot = 0;
      for (int j = 0; j < 8; ++j) if (j < e && r[j] > 0.f) slot = 1;
      int p = atomicAdd(&cnt, 1);
      eidx[e * 4096 + p] = t * 2 + slot;
      ewgt[e * 4096 + p] = wv;
    }
  }
  __syncthreads();
  int c = cnt;
  int padded = (c + 127) & ~127;
  for (int p = c + tid; p < padded; p += 256) eidx[e * 4096 + p] = -1;
  if (tid == 0) tcnt[e] = padded >> 7;  // tiles of 128 rows
}

// -------- gathered-A 128^2 MoE GEMM: Yp[slot][tok] = w * (x[tok] @ We^T + cbc_e) --------
__global__ __launch_bounds__(256) void k_moe128(const bf16_t* x_bf, const bf16_t* wexp_t,
                                                const int* eidx, const float* ewgt,
                                                const int* tcnt, const float* cbc, float* Yp) {
  int e = 0, ti = blockIdx.y;
  while (e < 8 && ti >= tcnt[e]) { ti -= tcnt[e]; ++e; }
  if (e >= 8) return;
  const int* idx = eidx + e * 4096 + ti * 128;
  const float* wgt = ewgt + e * 4096 + ti * 128;
  __shared__ bf16_t As[4096] __attribute__((aligned(16)));
  __shared__ bf16_t Bs[4096] __attribute__((aligned(16)));
  int tid = threadIdx.x, lane = tid & 63, w = tid >> 6;
  const bf16_t* aP[2];
#pragma unroll
  for (int r = 0; r < 2; ++r) {
    int row = r * 64 + w * 16 + (lane >> 2);
    int v = idx[row];
    int tok = (v < 0) ? 0 : (v >> 1);
    aP[r] = x_bf + (long)tok * 1024 + (lane & 3) * 8;
  }
  const bf16_t* Bb = wexp_t + (long)e * 1048576 + (long)blockIdx.x * 131072;
  int wr = w >> 1, wc = w & 1, lr = lane & 15, kg = lane >> 4;
  f32x4 acc[4][4];
  zero_acc(acc);
  for (int kt = 0; kt < 1024; kt += 32) {
    __syncthreads();
    gload_lds16(aP[0] + kt, As + (w * 16) * 32);
    gload_lds16(aP[1] + kt, As + (64 + w * 16) * 32);
    stage_tile(Bb + kt, 1024, Bs, tid);
    __syncthreads();
    bf16x8 a[4], b[4];
#pragma unroll
    for (int m = 0; m < 4; ++m)
      a[m] = *(const bf16x8*)&As[(wr * 64 + m * 16 + lr) * 32 + kg * 8];
#pragma unroll
    for (int n = 0; n < 4; ++n)
      b[n] = *(const bf16x8*)&Bs[(wc * 64 + n * 16 + lr) * 32 + kg * 8];
#pragma unroll
    for (int m = 0; m < 4; ++m)
#pragma unroll
      for (int n = 0; n < 4; ++n)
        acc[m][n] = __builtin_amdgcn_mfma_f32_16x16x32_bf16(a[m], b[n], acc[m][n], 0, 0, 0);
  }
  const float* cb = cbc + e * 1024 + blockIdx.x * 128;
#pragma unroll
  for (int m = 0; m < 4; ++m)
#pragma unroll
    for (int r = 0; r < 4; ++r) {
      int lrow = wr * 64 + m * 16 + kg * 4 + r;
      int v = idx[lrow];
      if (v < 0) continue;
      int tok = v >> 1, slot = v & 1;
      float wg = wgt[lrow];
      float* op = Yp + ((long)slot * 4096 + tok) * 1024 + blockIdx.x * 128;
#pragma unroll
      for (int n = 0; n < 4; ++n) {
        int gc = wc * 64 + n * 16 + lr;
        op[gc] = wg * (acc[m][n][r] + cb[gc]);
      }
    }
}

// ------------- combine the two expert slots -> bf16 -------------
__global__ __launch_bounds__(256) void k_combine2(const float* Yp, bf16_t* out) {
  long t = blockIdx.x;
  int d = threadIdx.x * 4;
  f32x4 a = *(const f32x4*)(Yp + t * 1024 + d);
  f32x4 b = *(const f32x4*)(Yp + 4194304L + t * 1024 + d);
  bf16x4 r;
#pragma unroll
  for (int i = 0; i < 4; ++i) r[i] = (bf16_t)(a[i] + b[i]);
  *(bf16x4*)(out + t * 1024 + d) = r;
}

// -------- batched bf16-out 128^2 GEMM with per-z f32 bias (q & k projections) --------
__global__ __launch_bounds__(256) void k_gemm_bias_bf16(const bf16_t* A, long Az,
                                                        const bf16_t* Bt, long Bz,
                                                        const float* bias0, const float* bias1,
                                                        bf16_t* out, long Oz, int K, int ldc) {
  __shared__ bf16_t As[4096] __attribute__((aligned(16)));
  __shared__ bf16_t Bs[4096] __attribute__((aligned(16)));
  int z = blockIdx.z;
  A += (long)z * Az; Bt += (long)z * Bz; out += (long)z * Oz;
  const float* bias = z ? bias1 : bias0;
  int rowBase = blockIdx.x * 128, colBase = blockIdx.y * 128;
  f32x4 acc[4][4];
  zero_acc(acc);
  gemm_core(A, Bt, K, K, K, rowBase, colBase, As, Bs, acc);
  int tid = threadIdx.x, lane = tid & 63, w = tid >> 6;
  int wr = w >> 1, wc = w & 1, lc = lane & 15, kg = lane >> 4;
#pragma unroll
  for (int m = 0; m < 4; ++m)
#pragma unroll
    for (int n = 0; n < 4; ++n)
#pragma unroll
      for (int r = 0; r < 4; ++r) {
        int gr = rowBase + wr * 64 + m * 16 + kg * 4 + r;
        int gc = colBase + wc * 64 + n * 16 + lc;
        out[(long)gr * ldc + gc] = (bf16_t)(acc[m][n][r] + bias[gc]);
      }
}

// ------------- 128^2 f32-out GEMM (QK^T) -------------
template <bool NT>
__global__ __launch_bounds__(256) void k_gemm128(
    const bf16_t* __restrict__ A, long Az, const bf16_t* __restrict__ Bt, long Bz,
    const float* __restrict__ bias, float* __restrict__ out, long Oz,
    int mB, int N, int K, float scale) {
  __shared__ bf16_t As[4096] __attribute__((aligned(16)));
  __shared__ bf16_t Bs[4096] __attribute__((aligned(16)));
  __shared__ float fl[32 * 132];
  int tid = threadIdx.x;
  A += (long)blockIdx.y * Az;
  Bt += (long)blockIdx.y * Bz;
  out += (long)blockIdx.y * Oz;
  int per = gridDim.x >> 3;
  int bid = blockIdx.x;
  int swz = (bid & 7) * per + (bid >> 3);
  int rowB = swz % mB, colB = swz / mB;
  int rowBase = rowB << 7, colBase = colB << 7;
  f32x4 acc[4][4];
  zero_acc(acc);
  gemm_core(A, Bt, K, K, K, rowBase, colBase, As, Bs, acc);
  int lane = tid & 63, w = tid >> 6;
  int wr = w >> 1, wc = w & 1, lc = lane & 15, kg = lane >> 4;
  int colq = (tid & 31) * 4;
  f32x4 bb = {0.f, 0.f, 0.f, 0.f};
  if (bias) bb = *(const f32x4*)(bias + colBase + colq);
#pragma unroll
  for (int c = 0; c < 4; ++c) {
    __syncthreads();
    if (wr == (c >> 1)) {
      int m0 = (c & 1) * 2;
#pragma unroll
      for (int mm = 0; mm < 2; ++mm)
#pragma unroll
        for (int n = 0; n < 4; ++n)
#pragma unroll
          for (int r = 0; r < 4; ++r)
            fl[(mm * 16 + kg * 4 + r) * 132 + wc * 64 + n * 16 + lc] = acc[m0 + mm][n][r] * scale;
    }
    __syncthreads();
    long grow = rowBase + c * 32;
#pragma unroll
    for (int q = 0; q < 4; ++q) {
      int idx = q * 256 + tid;
      int row = idx >> 5;
      f32x4 v = *(const f32x4*)&fl[row * 132 + colq];
      v += bb;
      float* op = out + (grow + row) * (long)N + colBase + colq;
      if (NT) __builtin_nontemporal_store(v, (f32x4*)op);
      else *(f32x4*)op = v;
    }
  }
}

// ------------- 256^2 BK=64 deep-pipelined GEMM, f32 out (logits) -------------
template <bool NT>
__global__ __launch_bounds__(512, 2) void k_gemm256(
    const bf16_t* __restrict__ A, long Az, const bf16_t* __restrict__ Bt, long Bz,
    const float* __restrict__ bias, float* __restrict__ out, long Oz,
    int mBlocks, int N, int K, int ntk, float scale) {
  __shared__ bf16_t lds[81920] __attribute__((aligned(16)));
  int tid = threadIdx.x;
  int lane = tid & 63, w = tid >> 6;
  int wr = w >> 2, wc = w & 3;
  int lr = lane & 15, kg = lane >> 4;
  A += (long)blockIdx.y * Az;
  Bt += (long)blockIdx.y * Bz;
  out += (long)blockIdx.y * Oz;
  int per = gridDim.x >> 3;
  int bid = blockIdx.x;
  int swz = (bid & 7) * per + (bid >> 3);
  int rowB = swz % mBlocks, colB = swz / mBlocks;
  long rowBase = (long)rowB << 8, colBase = (long)colB << 8;

  f32x4 acc[8][4];
#pragma unroll
  for (int m = 0; m < 8; ++m)
#pragma unroll
    for (int n = 0; n < 4; ++n)
#pragma unroll
      for (int i = 0; i < 4; ++i) acc[m][n][i] = 0.f;
  pipe256(A + rowBase * K, Bt + colBase * K, K, ntk, lds, acc);

  float* fl = (float*)lds;
  f32x4 bb4 = {0.f, 0.f, 0.f, 0.f};
  if (bias) bb4 = ((const f32x4*)(bias + colBase))[lane];
#pragma unroll
  for (int c = 0; c < 4; ++c) {
    if ((c >> 1) == wr) {
      int mg0 = (c & 1) * 4;
#pragma unroll
      for (int j = 0; j < 4; ++j)
#pragma unroll
        for (int n = 0; n < 4; ++n) {
          int col = wc * 64 + n * 16 + lr;
          int lrow = j * 16 + kg * 4;
#pragma unroll
          for (int rr = 0; rr < 4; ++rr)
            fl[(lrow + rr) * 260 + col] = acc[mg0 + j][n][rr] * scale;
        }
    }
    BAR();
    long grow = rowBase + c * 64;
#pragma unroll
    for (int q = 0; q < 8; ++q) {
      int r = w * 8 + q;
      f32x4 v = *(const f32x4*)&fl[r * 260 + lane * 4];
      v += bb4;
      float* op = out + (grow + r) * (long)N + colBase + lane * 4;
      if (NT) __builtin_nontemporal_store(v, (f32x4*)op);
      else *(f32x4*)op = v;
    }
    BAR();
  }
}

// ------------- 256^2 cache compressor: gelu + sigmoid-gated masked column-sum -------------
__global__ __launch_bounds__(512, 2) void k_cache256(
    const bf16_t* __restrict__ cache_bf, const bf16_t* __restrict__ wd_t,
    const float* __restrict__ ci, float* __restrict__ partial) {
  __shared__ bf16_t lds[81920] __attribute__((aligned(16)));
  int tid = threadIdx.x;
  int lane = tid & 63, w = tid >> 6;
  int wr = w >> 2, wc = w & 3;
  int lr = lane & 15, kg = lane >> 4;
  int e = blockIdx.y;
  const bf16_t* A = cache_bf + (long)e * 4194304;
  const bf16_t* Bt = wd_t + (long)e * 524288;
  int per = gridDim.x >> 3;
  int bid = blockIdx.x;
  int swz = (bid & 7) * per + (bid >> 3);
  int rowB = swz % 16, colB = swz / 16;
  long rowBase = (long)rowB << 8, colBase = (long)colB << 8;

  f32x4 acc[8][4];
#pragma unroll
  for (int m = 0; m < 8; ++m)
#pragma unroll
    for (int n = 0; n < 4; ++n)
#pragma unroll
      for (int i = 0; i < 4; ++i) acc[m][n][i] = 0.f;
  pipe256(A + rowBase * 1024, Bt + colBase * 1024, 1024, 16, lds, acc);

  float* colsum = (float*)lds;
  if (tid < 256) colsum[tid] = 0.f;
  __syncthreads();
  int csize = 4096 - 256 * e;
  const float* cie = ci + (long)e * 4096;
  float s[4] = {0.f, 0.f, 0.f, 0.f};
#pragma unroll
  for (int mg = 0; mg < 8; ++mg)
#pragma unroll
    for (int rr = 0; rr < 4; ++rr) {
      int row = (int)rowBase + wr * 128 + mg * 16 + kg * 4 + rr;
      float wf = (row < csize) ? 1.f / (1.f + expf(-cie[row])) : 0.f;
#pragma unroll
      for (int n = 0; n < 4; ++n) {
        float xv = acc[mg][n][rr];
        float t = xv + 0.044715f * xv * xv * xv;
        float gl = 0.5f * xv * (1.f + tanhf(0.7978845608028654f * t));
        s[n] += gl * wf;
      }
    }
#pragma unroll
  for (int n = 0; n < 4; ++n)
    atomicAdd(&colsum[wc * 64 + n * 16 + lr], s[n]);
  __syncthreads();
  if (tid < 256)
    partial[((long)e * 16 + rowB) * 512 + colB * 256 + tid] = colsum[tid];
}

// ------------- cached values: (fused reduce +) Wu matvec -> LoRA finalize -------------
__global__ __launch_bounds__(256) void k_wu_mv(const float* partial, const float* Wu, float* pre) {
  int e = blockIdx.x;
  int d = blockIdx.y * 256 + threadIdx.x;
  __shared__ float gs[512];
  for (int j = threadIdx.x; j < 512; j += 256) {
    float s = 0.f;
    for (int mx = 0; mx < 16; ++mx) s += partial[((long)e * 16 + mx) * 512 + j];
    gs[j] = s;
  }
  __syncthreads();
  const float* W = Wu + (long)e * 524288 + d;
  float s = 0.f;
  for (int j = 0; j < 512; ++j) s += gs[j] * W[(long)j * 1024];
  pre[e * 1024 + d] = s;
}

__global__ __launch_bounds__(256) void k_cached_fin(const float* pre, const float* Av,
                                                    const float* Bv, const float* bexp,
                                                    float* cbc) {
  int e = blockIdx.x, tid = threadIdx.x;
  __shared__ float ps[1024];
  __shared__ float tt[4];
  for (int d = tid; d < 1024; d += 256) ps[d] = pre[e * 1024 + d];
  __syncthreads();
  int w = tid >> 6, lane = tid & 63;
  {
    float s = 0.f;
    const float* Ave = Av + e * 4096;
    for (int d = lane; d < 1024; d += 64) s += ps[d] * Ave[d * 4 + w];
#pragma unroll
    for (int o = 32; o; o >>= 1) s += __shfl_xor(s, o);
    if (lane == 0) tt[w] = s;
  }
  __syncthreads();
  float inv = 1.f / (float)(4096 - 256 * e);
  const float* Bve = Bv + e * 4096;
  for (int d = tid; d < 1024; d += 256) {
    float lora = tt[0] * Bve[d] + tt[1] * Bve[1024 + d] + tt[2] * Bve[2048 + d] + tt[3] * Bve[3072 + d];
    cbc[e * 1024 + d] = (ps[d] + 0.25f * lora) * inv + bexp[e * 1024 + d];
  }
}

// ------------- attention row stats (single-pass online) + column sums -------------
__global__ __launch_bounds__(256) void k_rowstat(const float* S, float* mrow, float* zinv) {
  long row = blockIdx.x;
  const float* r = S + row * 2048;
  int tid = threadIdx.x;
  float m = -3.4e38f, s = 0.f;
  for (int c = tid; c < 2048; c += 256) {
    float v = r[c];
    if (v > m) { s = s * expf(m - v) + 1.f; m = v; }
    else s += expf(v - m);
  }
#pragma unroll
  for (int o = 32; o; o >>= 1) {
    float mo = __shfl_xor(m, o), so = __shfl_xor(s, o);
    float M = fmaxf(m, mo);
    s = s * expf(m - M) + so * expf(mo - M);
    m = M;
  }
  __shared__ float sm[4], ss[4];
  if ((tid & 63) == 0) { sm[tid >> 6] = m; ss[tid >> 6] = s; }
  __syncthreads();
  if (tid == 0) {
    float M = fmaxf(fmaxf(sm[0], sm[1]), fmaxf(sm[2], sm[3]));
    float S2 = ss[0] * expf(sm[0] - M) + ss[1] * expf(sm[1] - M) +
               ss[2] * expf(sm[2] - M) + ss[3] * expf(sm[3] - M);
    mrow[row] = M;
    zinv[row] = 1.f / S2;
  }
}

__global__ __launch_bounds__(256) void k_imp_part(const float* S, const float* mrow, const float* zinv,
                                                  float* ipart) {
  int k = blockIdx.x * 256 + threadIdx.x;
  int qc = blockIdx.y, b = blockIdx.z;
  const float* Sb = S + (long)b * 4194304;
  const float* mb = mrow + b * 2048;
  const float* zb = zinv + b * 2048;
  float s = 0.f;
  int q0 = qc * 128;
  for (int q = q0; q < q0 + 128; ++q)
    s += expf(Sb[(long)q * 2048 + k] - mb[q]) * zb[q];
  ipart[((long)b * 16 + qc) * 2048 + k] = s;
}

__global__ __launch_bounds__(256) void k_imp_fin(const float* ipart, float* out) {
  int k = blockIdx.x * 256 + threadIdx.x;
  int b = blockIdx.y;
  float s = 0.f;
  for (int qc = 0; qc < 16; ++qc) s += ipart[((long)b * 16 + qc) * 2048 + k];
  out[b * 2048 + k] = s;
}

extern "C" void kernel_launch(void* const* d_in, const int* in_sizes, int n_in,
                              void* d_out, int out_size, void* d_ws, size_t ws_size,
                              hipStream_t stream) {
  (void)in_sizes; (void)n_in; (void)out_size; (void)ws_size;
  const float* x    = (const float*)d_in[0];
  const float* query= (const float*)d_in[1];
  const float* cach = (const float*)d_in[2];
  const float* ci   = (const float*)d_in[3];
  const float* Wr   = (const float*)d_in[4];
  const float* Wexp = (const float*)d_in[5];
  const float* bexp = (const float*)d_in[6];
  const float* Aexp = (const float*)d_in[7];
  const float* Bexp = (const float*)d_in[8];
  const float* Wq   = (const float*)d_in[9];
  const float* bq   = (const float*)d_in[10];
  const float* Wk   = (const float*)d_in[11];
  const float* bk   = (const float*)d_in[12];
  const float* Aq   = (const float*)d_in[13];
  const float* Bq   = (const float*)d_in[14];
  const float* Ak   = (const float*)d_in[15];
  const float* Bk   = (const float*)d_in[16];
  const float* Wd   = (const float*)d_in[17];
  const float* Wu   = (const float*)d_in[18];
  const float* Av   = (const float*)d_in[19];
  const float* Bv   = (const float*)d_in[20];
  const float* Wv   = (const float*)d_in[21];
  const float* bv   = (const float*)d_in[22];
  float* out = (float*)d_out;

  size_t off = 0;
  char* base = (char*)d_ws;
  auto carve = [&](size_t bytes) { char* p = base + off; off = (off + bytes + 255) & ~(size_t)255; return (void*)p; };
  bf16_t* query_bf = (bf16_t*)carve(8388608);
  bf16_t* x_bf     = (bf16_t*)carve(8388608);   // = query_bf + 4194304 (contiguous for k_cast2)
  bf16_t* q_bf     = (bf16_t*)carve(8388608);
  bf16_t* k_bf     = (bf16_t*)carve(8388608);   // = q_bf + 4194304
  bf16_t* expert_bf= (bf16_t*)carve(8388608);
  bf16_t* wq_t     = (bf16_t*)carve(2097152);
  bf16_t* wk_t     = (bf16_t*)carve(2097152);   // = wq_t + 1048576
  bf16_t* wd_t     = (bf16_t*)carve(8388608);
  bf16_t* wexp_t   = (bf16_t*)carve(16777216);
  float*  s_att    = (float*)carve(33554432);
  float*  mrow     = (float*)carve(16384);
  float*  zinv     = (float*)carve(16384);
  float*  rw       = (float*)carve(131072);
  float*  partial  = (float*)carve(262144);
  float*  pre      = (float*)carve(32768);
  float*  cbc      = (float*)carve(32768);
  float*  ipart    = (float*)carve(262144);
  int*    eidx     = (int*)carve(131072);
  float*  ewgt     = (float*)carve(131072);
  int*    tcnt     = (int*)carve(256);
  // uni region time-shares (stream-ordered): cache_bf -> Yp (MoE outputs) -> wv_t
  void*   uni      = carve(71303168);  // 68 MB
  bf16_t* cache_bf = (bf16_t*)uni;
  float*  Yp       = (float*)uni;      // 2 x 4096 x 1024 f32 = 33.5 MB
  bf16_t* wv_t     = (bf16_t*)uni;

  // casts
  k_cast2<<<8192, 256, 0, stream>>>(query, x, query_bf);
  k_cast<<<32768, 256, 0, stream>>>(cach, cache_bf, 8388608);
  // merged-LoRA transposed weights
  k_prep_wt<<<dim3(16, 16, 1), 256, 0, stream>>>(Wq, Aq, Bq, wq_t, 1024, 1024, 0, 0, 0, 0);
  k_prep_wt<<<dim3(16, 16, 1), 256, 0, stream>>>(Wk, Ak, Bk, wk_t, 1024, 1024, 0, 0, 0, 0);
  k_prep_wt<<<dim3(16, 8, 8), 256, 0, stream>>>(Wd, nullptr, nullptr, wd_t, 1024, 512, 524288, 0, 0, 524288);
  k_prep_wt<<<dim3(16, 16, 8), 256, 0, stream>>>(Wexp, Aexp, Bexp, wexp_t, 1024, 1024, 1048576, 4096, 4096, 1048576);
  // router + MoE schedule
  k_router<<<1024, 256, 0, stream>>>(x, Wr, rw);
  k_sched<<<8, 256, 0, stream>>>(rw, eidx, ewgt, tcnt);
  // q & k projections in one batched launch
  k_gemm_bias_bf16<<<dim3(32, 8, 2), 256, 0, stream>>>(query_bf, 4194304, wq_t, 1048576,
                                                       bq, bk, q_bf, 4194304, 1024, 1024);
  // attention scores + importance
  k_gemm128<false><<<dim3(256, 2), 256, 0, stream>>>(q_bf, 2097152, k_bf, 2097152, nullptr,
                                                     s_att, 4194304, 16, 2048, 1024, 0.03125f);
  k_rowstat<<<4096, 256, 0, stream>>>(s_att, mrow, zinv);
  k_imp_part<<<dim3(8, 16, 2), 256, 0, stream>>>(s_att, mrow, zinv, ipart);
  k_imp_fin<<<dim3(8, 2), 256, 0, stream>>>(ipart, out + 131072000L);
  // cache compressor -> cached values
  k_cache256<<<dim3(32, 8), 512, 0, stream>>>(cache_bf, wd_t, ci, partial);
  k_wu_mv<<<dim3(8, 4), 256, 0, stream>>>(partial, Wu, pre);
  k_cached_fin<<<8, 256, 0, stream>>>(pre, Av, Bv, bexp, cbc);
  // top-2 gather-GEMM (writes Yp over cache_bf region; cache256 already consumed it)
  k_moe128<<<dim3(8, 72), 256, 0, stream>>>(x_bf, wexp_t, eidx, ewgt, tcnt, cbc, Yp);
  k_combine2<<<4096, 256, 0, stream>>>(Yp, expert_bf);
  // vocab projection (wv_t reuses uni after combine consumed Yp; BK=64 free-run pipe)
  k_prep_wt<<<dim3(16, 500, 1), 256, 0, stream>>>(Wv, nullptr, nullptr, wv_t, 1024, 32000, 0, 0, 0, 0);
  k_gemm256<true><<<dim3(2000, 1), 512, 0, stream>>>(expert_bf, 0, wv_t, 0, bv,
                                                     out, 0, 16, 32000, 1024, 16, 1.0f);
}